// Round 8
// baseline (228.924 us; speedup 1.0000x reference)
//
#include <hip/hip_runtime.h>
#include <stdint.h>

#define B_ 2
#define S_ 2048
#define D_ 1024
#define H_ 16
#define DH_ 64
#define DFF_ 4096
#define NROW_ (B_*S_)
#define KVB_ 64
#define RS_ 3

typedef __attribute__((ext_vector_type(8))) short bf16x8;
typedef __attribute__((ext_vector_type(4))) float f32x4;
typedef __attribute__((ext_vector_type(16))) float f32x16;
typedef __attribute__((ext_vector_type(4))) unsigned int u32x4;

__device__ __forceinline__ float bf2f(unsigned short u) {
  union { unsigned int i; float f; } v; v.i = ((unsigned int)u) << 16; return v.f;
}
__device__ __forceinline__ unsigned short f2bf(float f) {
  union { float f; unsigned int i; } v; v.f = f;
  unsigned int r = v.i + 0x7fffu + ((v.i >> 16) & 1u);
  return (unsigned short)(r >> 16);
}

__device__ __forceinline__ void gload16(const void* g, void* l) {
  __builtin_amdgcn_global_load_lds(
      (const __attribute__((address_space(1))) unsigned int*)(uintptr_t)g,
      (__attribute__((address_space(3))) unsigned int*)(unsigned int)(uintptr_t)l,
      16, 0, 0);
}

// T1 XCD-chunked swizzle of the xy-plane (requires nwg%8==0; all our grids are)
__device__ __forceinline__ void xcd_swz(int& bx, int& by) {
  const int gx = gridDim.x, nwg = gx * gridDim.y;
  const int flat = blockIdx.y * gx + blockIdx.x;
  const int chunk = nwg >> 3;
  const int nf = (flat & 7) * chunk + (flat >> 3);
  bx = nf % gx; by = nf / gx;
}

__global__ __launch_bounds__(256)
void k_cvt(const float* __restrict__ in, unsigned short* __restrict__ out, int n) {
  int i = (blockIdx.x * 256 + threadIdx.x) * 4;
  if (i < n) {
    float4 f = *(const float4*)(in + i);
    ushort4 o; o.x = f2bf(f.x); o.y = f2bf(f.y); o.z = f2bf(f.z); o.w = f2bf(f.w);
    *(ushort4*)(out + i) = o;
  }
}

__global__ __launch_bounds__(256)
void k_cat3(const float* __restrict__ a, const float* __restrict__ b,
            const float* __restrict__ c, float* __restrict__ o) {
  int i = blockIdx.x * 256 + threadIdx.x;
  if (i < 3 * D_)
    o[i] = i < D_ ? a[i] : (i < 2 * D_ ? b[i - D_] : c[i - 2 * D_]);
}

// fused 4x DxD convert+transpose (z picks the matrix)
__global__ __launch_bounds__(256)
void k_cvt_t4(const float* __restrict__ w0, const float* __restrict__ w1,
              const float* __restrict__ w2, const float* __restrict__ w3,
              unsigned short* __restrict__ o0, unsigned short* __restrict__ o1,
              unsigned short* __restrict__ o2, unsigned short* __restrict__ o3) {
  __shared__ float tile[32][33];
  const int z = blockIdx.z;
  const float* in = z == 0 ? w0 : z == 1 ? w1 : z == 2 ? w2 : w3;
  unsigned short* out = z == 0 ? o0 : z == 1 ? o1 : z == 2 ? o2 : o3;
  const int k0 = blockIdx.y * 32, n0 = blockIdx.x * 32;
  const int tx = threadIdx.x & 31, ty = threadIdx.x >> 5;
  #pragma unroll
  for (int i = 0; i < 32; i += 8)
    tile[ty + i][tx] = in[(size_t)(k0 + ty + i) * D_ + n0 + tx];
  __syncthreads();
  #pragma unroll
  for (int i = 0; i < 32; i += 8)
    out[(size_t)(n0 + ty + i) * D_ + k0 + tx] = f2bf(tile[tx][ty + i]);
}

__global__ __launch_bounds__(256)
void k_cvt_t(const float* __restrict__ in, unsigned short* __restrict__ out,
             int K, int N) {
  __shared__ float tile[32][33];
  const int k0 = blockIdx.y * 32, n0 = blockIdx.x * 32;
  const int tx = threadIdx.x & 31, ty = threadIdx.x >> 5;
  #pragma unroll
  for (int i = 0; i < 32; i += 8)
    tile[ty + i][tx] = in[(size_t)(k0 + ty + i) * N + n0 + tx];
  __syncthreads();
  #pragma unroll
  for (int i = 0; i < 32; i += 8)
    out[(size_t)(n0 + ty + i) * K + k0 + tx] = f2bf(tile[tx][ty + i]);
}

__global__ __launch_bounds__(256)
void k_tr_v(const unsigned short* __restrict__ v, unsigned short* __restrict__ vt) {
  __shared__ unsigned short tile[32][33];
  const int b = blockIdx.z;
  const int s0 = blockIdx.y * 32, c0 = blockIdx.x * 32;
  const int tx = threadIdx.x & 31, ty = threadIdx.x >> 5;
  #pragma unroll
  for (int i = 0; i < 32; i += 8)
    tile[ty + i][tx] = v[((size_t)(b * S_ + s0 + ty + i)) * D_ + c0 + tx];
  __syncthreads();
  #pragma unroll
  for (int i = 0; i < 32; i += 8)
    vt[((size_t)(b * D_ + c0 + ty + i)) * S_ + s0 + tx] = tile[tx][ty + i];
}

// =================== 256-tile deep-pipelined GEMM (T2+T3+T4+T5) ===================
// EPI: 1 = relu bf16, 3 = QKV split (q pre-scaled 0.125*log2e), 4 = split-K bf16 partial.
template<int BM, int BN, int WR, int WC, int EPI>
__global__ __launch_bounds__(512, 2)
void k_gemm8(const unsigned short* __restrict__ A,
             const unsigned short* __restrict__ Bt,
             const float* __restrict__ bias,
             void* __restrict__ out, int M, int N, int K, int KCH) {
  constexpr int FM = BM / WR / 16;
  constexpr int FN = BN / WC / 16;
  constexpr int LPA = BM / 128;
  constexpr int LPB = BN / 128;
  constexpr int LPS = LPA + LPB;
  __shared__ unsigned short Al[4][BM * 32];
  __shared__ unsigned short Bl[4][BN * 32];

  const int tid = threadIdx.x;
  const int wave = tid >> 6, l = tid & 63;
  const int wm = wave / WC, wn = wave % WC;
  const int g = l >> 4, c = l & 15;
  int bx, by; xcd_swz(bx, by);
  const int m0 = by * BM, n0 = bx * BN;
  const int kbeg = (EPI == 4) ? blockIdx.z * KCH : 0;
  const int nt = ((EPI == 4) ? KCH : K) >> 5;

  f32x4 acc[FM][FN] = {};

  auto stage = [&](int t) {
    const int kt = kbeg + t * 32;
    unsigned short* Ab = &Al[t & 3][0];
    unsigned short* Bb = &Bl[t & 3][0];
    #pragma unroll
    for (int p = 0; p < LPA; ++p) {
      const int o = tid * 16 + p * 8192;
      const int row = o >> 6;
      const int cb = (o & 63) ^ (((row >> 1) & 3) << 4);
      gload16(A + (size_t)(m0 + row) * K + kt + (cb >> 1), Ab + (o >> 1));
    }
    #pragma unroll
    for (int p = 0; p < LPB; ++p) {
      const int o = tid * 16 + p * 8192;
      const int row = o >> 6;
      const int cb = (o & 63) ^ (((row >> 1) & 3) << 4);
      gload16(Bt + (size_t)(n0 + row) * K + kt + (cb >> 1), Bb + (o >> 1));
    }
  };

  stage(0); stage(1); stage(2);

  for (int t = 0; t < nt; ++t) {
    if (t <= nt - 3) {
      if constexpr (LPS == 4) asm volatile("s_waitcnt vmcnt(8)" ::: "memory");
      else                    asm volatile("s_waitcnt vmcnt(6)" ::: "memory");
    } else if (t == nt - 2) {
      if constexpr (LPS == 4) asm volatile("s_waitcnt vmcnt(4)" ::: "memory");
      else                    asm volatile("s_waitcnt vmcnt(3)" ::: "memory");
    } else {
      asm volatile("s_waitcnt vmcnt(0)" ::: "memory");
    }
    asm volatile("s_barrier" ::: "memory");

    const unsigned short* Ab = &Al[t & 3][0];
    const unsigned short* Bb = &Bl[t & 3][0];
    bf16x8 af[FM], bf[FN];
    #pragma unroll
    for (int i = 0; i < FM; ++i) {
      const int row = wm * (BM / WR) + i * 16 + c;
      af[i] = *(const bf16x8*)(Ab + row * 32 + (((g * 16) ^ (((row >> 1) & 3) << 4)) >> 1));
    }
    #pragma unroll
    for (int j = 0; j < FN; ++j) {
      const int row = wn * (BN / WC) + j * 16 + c;
      bf[j] = *(const bf16x8*)(Bb + row * 32 + (((g * 16) ^ (((row >> 1) & 3) << 4)) >> 1));
    }
    if (t + 3 < nt) stage(t + 3);

    __builtin_amdgcn_s_setprio(1);
    #pragma unroll
    for (int i = 0; i < FM; ++i)
      #pragma unroll
      for (int j = 0; j < FN; ++j)
        acc[i][j] = __builtin_amdgcn_mfma_f32_16x16x32_bf16(af[i], bf[j], acc[i][j], 0, 0, 0);
    __builtin_amdgcn_s_setprio(0);
  }

  #pragma unroll
  for (int j = 0; j < FN; ++j) {
    const int col = n0 + wn * (BN / WC) + j * 16 + c;
    float bv;
    if (EPI == 4) bv = (blockIdx.z == 0) ? bias[col] : 0.f;
    else          bv = bias[col];
    #pragma unroll
    for (int i = 0; i < FM; ++i) {
      #pragma unroll
      for (int r = 0; r < 4; ++r) {
        const int row = m0 + wm * (BM / WR) + i * 16 + g * 4 + r;
        float v = acc[i][j][r] + bv;
        if (EPI == 1) v = fmaxf(v, 0.f);
        if (EPI == 3) {
          if (col < D_) v *= 0.18033688f;   // 1/sqrt(DH) * log2(e): softmax via exp2
          ((unsigned short*)out)[(size_t)(col >> 10) * ((size_t)NROW_ * D_) +
                                 (size_t)row * D_ + (col & (D_ - 1))] = f2bf(v);
        } else if (EPI == 4) {
          ((unsigned short*)out)[(size_t)blockIdx.z * M * N + (size_t)row * N + col] =
              f2bf(v);
        } else {
          ((unsigned short*)out)[(size_t)row * N + col] = f2bf(v);
        }
      }
    }
  }
}

// ---------------- flash attention, KV-split x2 -> O/l partials ----------------
// Grid (16 qblk, 32 bh, 2 kv-half) -> 1024 blocks (~3/CU with 48KB LDS ring).
// Writes P[z][bh][s][dh] bf16 (unnormalized O) and lbuf[z][bh][s] fp32; a
// merge kernel computes (P0+P1)/(l0+l1). Custom XCD swizzle keeps one (b,h)'s
// 32 blocks (all q, both halves) on one XCD -> K/V L2-resident.
__global__ __launch_bounds__(256, 3)
void k_attn(const unsigned short* __restrict__ q,
            const unsigned short* __restrict__ k,
            const unsigned short* __restrict__ vt,
            unsigned short* __restrict__ P, float* __restrict__ lbuf) {
  __shared__ unsigned short Kl[RS_][64 * 64];
  __shared__ unsigned short Vl[RS_][64 * 64];
  const int tid = threadIdx.x, wave = tid >> 6, l = tid & 63;
  // swizzle: flat grouped by bh (32 consecutive = one bh) -> 4 bh per XCD chunk
  const int flat = blockIdx.y * 32 + blockIdx.z * 16 + blockIdx.x;
  const int nf = (flat & 7) * 128 + (flat >> 3);
  const int bh = nf >> 5, rem = nf & 31;
  const int bz = rem >> 4, bx = rem & 15;
  const int b = bh >> 4, h = bh & 15;
  const int q0 = bx * 128 + wave * 32;
  const int kvoff = bz * (S_ / 2);
  const int c32 = l & 31, hi = l >> 5;

  const unsigned short* qp = q + ((size_t)(b * S_ + q0 + c32)) * D_ + h * DH_ + hi * 8;
  bf16x8 qf[4];
  #pragma unroll
  for (int ks = 0; ks < 4; ++ks) qf[ks] = *(const bf16x8*)(qp + ks * 16);

  const unsigned short* kbase = k + ((size_t)(b * S_ + kvoff)) * D_ + h * DH_;
  const unsigned short* vbase = vt + ((size_t)bh) * DH_ * S_ + kvoff;

  f32x16 acc0 = {}, acc1 = {};
  float l_r = 0.f;

  auto stage = [&](int t) {
    const int kv0 = t * KVB_;
    unsigned short* Kb = &Kl[t % RS_][0];
    unsigned short* Vb = &Vl[t % RS_][0];
    #pragma unroll
    for (int p = 0; p < 2; ++p) {
      const int o = tid * 16 + p * 4096;
      const int r = o >> 7, cb = (o & 127) ^ ((r & 7) << 4);
      gload16(kbase + (size_t)(kv0 + r) * D_ + (cb >> 1), Kb + (o >> 1));
      gload16(vbase + (size_t)r * S_ + kv0 + (cb >> 1), Vb + (o >> 1));
    }
  };

  stage(0); stage(1);
  const int nt = (S_ / 2) / KVB_;   // 16
  for (int t = 0; t < nt; ++t) {
    if (t < nt - 1) asm volatile("s_waitcnt vmcnt(4)" ::: "memory");
    else            asm volatile("s_waitcnt vmcnt(0)" ::: "memory");
    asm volatile("s_barrier" ::: "memory");
    if (t + 2 < nt) stage(t + 2);
    const char* Kb = (const char*)&Kl[t % RS_][0];
    const char* Vb = (const char*)&Vl[t % RS_][0];

    f32x16 s0 = {}, s1 = {};
    __builtin_amdgcn_s_setprio(1);
    #pragma unroll
    for (int ks = 0; ks < 4; ++ks) {
      const int row0 = c32, row1 = 32 + c32;
      const int db = ks * 32 + hi * 16;
      bf16x8 kf0 = *(const bf16x8*)(Kb + row0 * 128 + (db ^ ((row0 & 7) << 4)));
      bf16x8 kf1 = *(const bf16x8*)(Kb + row1 * 128 + (db ^ ((row1 & 7) << 4)));
      s0 = __builtin_amdgcn_mfma_f32_32x32x16_bf16(kf0, qf[ks], s0, 0, 0, 0);
      s1 = __builtin_amdgcn_mfma_f32_32x32x16_bf16(kf1, qf[ks], s1, 0, 0, 0);
    }
    __builtin_amdgcn_s_setprio(0);

    #pragma unroll
    for (int r = 0; r < 16; ++r) {
      asm("v_exp_f32 %0, %1" : "=v"(s0[r]) : "v"(s0[r]));
      asm("v_exp_f32 %0, %1" : "=v"(s1[r]) : "v"(s1[r]));
    }
    float p0 = 0.f, p1 = 0.f;
    #pragma unroll
    for (int r = 0; r < 16; ++r) { p0 += s0[r]; p1 += s1[r]; }
    float sm = p0 + p1;
    sm += __shfl_xor(sm, 32);
    l_r += sm;

    unsigned int W0[8], W1[8];
    #pragma unroll
    for (int i = 0; i < 8; ++i) {
      asm("v_cvt_pk_bf16_f32 %0, %1, %2" : "=v"(W0[i]) : "v"(s0[2*i]), "v"(s0[2*i+1]));
      asm("v_cvt_pk_bf16_f32 %0, %1, %2" : "=v"(W1[i]) : "v"(s1[2*i]), "v"(s1[2*i+1]));
    }
    #pragma unroll
    for (int kk = 0; kk < 2; ++kk) {
      asm volatile("v_permlane32_swap_b32 %0, %1" : "+v"(W0[4*kk]),   "+v"(W0[4*kk+2]));
      asm volatile("v_permlane32_swap_b32 %0, %1" : "+v"(W0[4*kk+1]), "+v"(W0[4*kk+3]));
      asm volatile("v_permlane32_swap_b32 %0, %1" : "+v"(W1[4*kk]),   "+v"(W1[4*kk+2]));
      asm volatile("v_permlane32_swap_b32 %0, %1" : "+v"(W1[4*kk+1]), "+v"(W1[4*kk+3]));
    }

    __builtin_amdgcn_s_setprio(1);
    #pragma unroll
    for (int m = 0; m < 4; ++m) {
      const unsigned int* Wt = (m < 2) ? W0 : W1;
      const int kk = m & 1;
      union { unsigned int u[4]; bf16x8 v; } pk;
      pk.u[0] = Wt[4*kk]; pk.u[1] = Wt[4*kk+1];
      pk.u[2] = Wt[4*kk+2]; pk.u[3] = Wt[4*kk+3];
      const int row0 = c32, row1 = 32 + c32;
      const int db = m * 32 + hi * 16;
      bf16x8 vf0 = *(const bf16x8*)(Vb + row0 * 128 + (db ^ ((row0 & 7) << 4)));
      bf16x8 vf1 = *(const bf16x8*)(Vb + row1 * 128 + (db ^ ((row1 & 7) << 4)));
      acc0 = __builtin_amdgcn_mfma_f32_32x32x16_bf16(pk.v, vf0, acc0, 0, 0, 0);
      acc1 = __builtin_amdgcn_mfma_f32_32x32x16_bf16(pk.v, vf1, acc1, 0, 0, 0);
    }
    __builtin_amdgcn_s_setprio(0);
  }

  // write partials: P[(bz*32+bh)][q][dh] (no normalization), l once per q-row
  unsigned short* pout = P + ((size_t)(bz * 32 + bh) * S_) * DH_;
  if (hi == 0) lbuf[(size_t)(bz * 32 + bh) * S_ + q0 + c32] = l_r;
  #pragma unroll
  for (int r = 0; r < 16; ++r) {
    const int qq = (r & 3) + 8 * (r >> 2) + 4 * hi;
    const size_t rowb = (size_t)(q0 + qq) * DH_ + c32;
    pout[rowb]      = f2bf(acc0[r]);
    pout[rowb + 32] = f2bf(acc1[r]);
  }
}

// merge: ctx[b,s,h,dh] = (P0 + P1) / (l0 + l1)
__global__ __launch_bounds__(256)
void k_attn_merge(const unsigned short* __restrict__ P,
                  const float* __restrict__ lbuf,
                  unsigned short* __restrict__ ctx) {
  const int i4 = (blockIdx.x * 256 + threadIdx.x) * 4;
  const int dh = i4 & 63;
  const int h  = (i4 >> 6) & 15;
  const int s  = (i4 >> 10) & (S_ - 1);
  const int b  = i4 >> 21;
  const int bh = b * 16 + h;
  const size_t pi = ((size_t)bh * S_ + s) * DH_ + dh;
  const size_t zoff = (size_t)32 * S_ * DH_;
  ushort4 pa = *(const ushort4*)(P + pi);
  ushort4 pb = *(const ushort4*)(P + pi + zoff);
  const float l0 = lbuf[(size_t)bh * S_ + s];
  const float l1 = lbuf[(size_t)bh * S_ + s + 32 * S_];
  const float inv = 1.0f / (l0 + l1);
  ushort4 o;
  o.x = f2bf((bf2f(pa.x) + bf2f(pb.x)) * inv);
  o.y = f2bf((bf2f(pa.y) + bf2f(pb.y)) * inv);
  o.z = f2bf((bf2f(pa.z) + bf2f(pb.z)) * inv);
  o.w = f2bf((bf2f(pa.w) + bf2f(pb.w)) * inv);
  *(ushort4*)(ctx + (size_t)i4) = o;
}

// ---------------- LayerNorm (one row per block), two bf16 partials ----------------
template<int MODE>
__global__ __launch_bounds__(256)
void k_ln(const void* __restrict__ res, const unsigned short* __restrict__ y0,
          const unsigned short* __restrict__ y1,
          const float* __restrict__ gamma, const float* __restrict__ beta,
          void* __restrict__ out) {
  const int row = blockIdx.x, tid = threadIdx.x;
  const size_t base = (size_t)row * D_ + tid * 4;
  ushort4 ya = *(const ushort4*)(y0 + base);
  ushort4 yb = *(const ushort4*)(y1 + base);
  float h[4];
  if (MODE == 0) {
    float4 xv = *(const float4*)((const float*)res + base);
    h[0] = xv.x + bf2f(ya.x) + bf2f(yb.x); h[1] = xv.y + bf2f(ya.y) + bf2f(yb.y);
    h[2] = xv.z + bf2f(ya.z) + bf2f(yb.z); h[3] = xv.w + bf2f(ya.w) + bf2f(yb.w);
  } else {
    ushort4 xv = *(const ushort4*)((const unsigned short*)res + base);
    h[0] = bf2f(xv.x) + bf2f(ya.x) + bf2f(yb.x); h[1] = bf2f(xv.y) + bf2f(ya.y) + bf2f(yb.y);
    h[2] = bf2f(xv.z) + bf2f(ya.z) + bf2f(yb.z); h[3] = bf2f(xv.w) + bf2f(ya.w) + bf2f(yb.w);
  }
  float s = h[0] + h[1] + h[2] + h[3];
  float q = h[0]*h[0] + h[1]*h[1] + h[2]*h[2] + h[3]*h[3];
  #pragma unroll
  for (int m = 1; m < 64; m <<= 1) { s += __shfl_xor(s, m); q += __shfl_xor(q, m); }
  __shared__ float red[8];
  if ((tid & 63) == 0) { red[tid >> 6] = s; red[4 + (tid >> 6)] = q; }
  __syncthreads();
  s = red[0] + red[1] + red[2] + red[3];
  q = red[4] + red[5] + red[6] + red[7];
  const float mu = s * (1.0f / D_);
  const float rstd = rsqrtf(q * (1.0f / D_) - mu * mu + 1e-5f);
  const int c0 = tid * 4;
  float4 gv = *(const float4*)(gamma + c0);
  float4 bv = *(const float4*)(beta + c0);
  float o0 = (h[0] - mu) * rstd * gv.x + bv.x;
  float o1 = (h[1] - mu) * rstd * gv.y + bv.y;
  float o2 = (h[2] - mu) * rstd * gv.z + bv.z;
  float o3 = (h[3] - mu) * rstd * gv.w + bv.w;
  if (MODE == 0) {
    ushort4 ov; ov.x = f2bf(o0); ov.y = f2bf(o1); ov.z = f2bf(o2); ov.w = f2bf(o3);
    *(ushort4*)((unsigned short*)out + base) = ov;
  } else {
    float4 ov; ov.x = o0; ov.y = o1; ov.z = o2; ov.w = o3;
    *(float4*)((float*)out + base) = ov;
  }
}

extern "C" void kernel_launch(void* const* d_in, const int* in_sizes, int n_in,
                              void* d_out, int out_size, void* d_ws, size_t ws_size,
                              hipStream_t stream) {
  const float* x   = (const float*)d_in[0];
  const float* Wq  = (const float*)d_in[2];
  const float* bq  = (const float*)d_in[3];
  const float* Wk  = (const float*)d_in[4];
  const float* bk  = (const float*)d_in[5];
  const float* Wv  = (const float*)d_in[6];
  const float* bv  = (const float*)d_in[7];
  const float* Wo  = (const float*)d_in[8];
  const float* bo  = (const float*)d_in[9];
  const float* W0  = (const float*)d_in[10];
  const float* b0  = (const float*)d_in[11];
  const float* W1  = (const float*)d_in[12];
  const float* b1  = (const float*)d_in[13];
  const float* g0  = (const float*)d_in[14];
  const float* be0 = (const float*)d_in[15];
  const float* g1  = (const float*)d_in[16];
  const float* be1 = (const float*)d_in[17];

  char* ws = (char*)d_ws;
  const size_t MB = 1024 * 1024;
  // live ranges (MiB):
  //  [0,8)   xb -> vtb (read by attn) -> FFN2 partials fp [0,16)
  //  [8,14)  wqkvT (dead after QKV) -> lbuf at [8,9)
  //  [14,16) woT (dead after Wo)
  //  [16,24) w0T   [24,32) w1T
  //  [32,40) qb, [40,48) kb (dead after attn) -> Wo partials ap [32,48)
  //  [48,56) vb -> ctxb (merge out) -> h0b (LN1 out, after Wo reads ctxb)
  //  [56,72) attn O-partials P (dead after merge) -> ff1 [56,88)
  //  [64,88) bcat (dead after QKV) / ff1 tail
  unsigned short* xb   = (unsigned short*)(ws);
  unsigned short* vtb  = (unsigned short*)(ws);
  unsigned short* wqT  = (unsigned short*)(ws + 8 * MB);
  unsigned short* woT  = (unsigned short*)(ws + 14 * MB);
  unsigned short* w0T  = (unsigned short*)(ws + 16 * MB);
  unsigned short* w1T  = (unsigned short*)(ws + 24 * MB);
  unsigned short* qb   = (unsigned short*)(ws + 32 * MB);
  unsigned short* kb   = (unsigned short*)(ws + 40 * MB);
  unsigned short* vb   = (unsigned short*)(ws + 48 * MB);
  unsigned short* ctxb = (unsigned short*)(ws + 48 * MB);  // merge out (vb dead)
  unsigned short* ap   = (unsigned short*)(ws + 32 * MB);  // Wo partials [32,48)
  unsigned short* h0b  = (unsigned short*)(ws + 48 * MB);  // LN1 out (ctxb dead)
  unsigned short* Pp   = (unsigned short*)(ws + 56 * MB);  // attn partials [56,72)
  float*          lbuf = (float*)(ws + 8 * MB);            // [8,8.5)
  unsigned short* ff1  = (unsigned short*)(ws + 56 * MB);  // [56,88)
  unsigned short* fp   = (unsigned short*)(ws);            // FFN2 partials [0,16)
  float*          bcat = (float*)(ws + 80 * MB);

  k_cvt<<<4096, 256, 0, stream>>>(x, xb, NROW_ * D_);
  k_cat3<<<12, 256, 0, stream>>>(bq, bk, bv, bcat);
  k_cvt_t4<<<dim3(32, 32, 4), 256, 0, stream>>>(
      Wq, Wk, Wv, Wo,
      wqT, wqT + (size_t)D_ * D_, wqT + 2 * (size_t)D_ * D_, woT);
  k_cvt_t<<<dim3(128, 32), 256, 0, stream>>>(W0, w0T, D_, DFF_);
  k_cvt_t<<<dim3(32, 128), 256, 0, stream>>>(W1, w1T, DFF_, D_);

  // QKV: 256x256 tiles, grid 12x16 = 192
  k_gemm8<256, 256, 2, 4, 3><<<dim3(3 * D_ / 256, NROW_ / 256), 512, 0, stream>>>(
      xb, wqT, bcat, qb, NROW_, 3 * D_, D_, 0);

  k_tr_v<<<dim3(D_ / 32, S_ / 32, B_), 256, 0, stream>>>(vb, vtb);

  // attention: KV-split x2 -> partials, then merge
  k_attn<<<dim3(S_ / 128, B_ * H_, 2), 256, 0, stream>>>(qb, kb, vtb, Pp, lbuf);
  k_attn_merge<<<(NROW_ * D_) / 1024, 256, 0, stream>>>(Pp, lbuf, ctxb);

  // Wo: 256x128 tiles, split-K x2 (KCH=512), grid 8x16x2 = 256
  k_gemm8<256, 128, 4, 2, 4><<<dim3(D_ / 128, NROW_ / 256, 2), 512, 0, stream>>>(
      ctxb, woT, bo, ap, NROW_, D_, D_, D_ / 2);
  k_ln<0><<<NROW_, 256, 0, stream>>>(x, ap, ap + (size_t)NROW_ * D_, g0, be0, h0b);

  // FFN1: 256x256 tiles, grid 16x16 = 256
  k_gemm8<256, 256, 2, 4, 1><<<dim3(DFF_ / 256, NROW_ / 256), 512, 0, stream>>>(
      h0b, w0T, b0, ff1, NROW_, DFF_, D_, 0);
  // FFN2: 256x128 tiles, split-K x2 (KCH=2048), grid 8x16x2 = 256
  k_gemm8<256, 128, 4, 2, 4><<<dim3(D_ / 128, NROW_ / 256, 2), 512, 0, stream>>>(
      ff1, w1T, b1, fp, NROW_, D_, DFF_, DFF_ / 2);
  k_ln<1><<<NROW_, 256, 0, stream>>>(h0b, fp, fp + (size_t)NROW_ * D_, g1, be1, (float*)d_out);

  (void)vtb; (void)ws_size; (void)n_in; (void)in_sizes; (void)out_size;
}